// Round 7
// baseline (91.167 us; speedup 1.0000x reference)
//
#include <hip/hip_runtime.h>
#include <hip/hip_bf16.h>

#define BATCH 8
#define SEQ   2048
#define DMS   1024
#define KSZ   128
#define OD    1152   // 1024 + 128

typedef unsigned short u16;
typedef unsigned int   u32;
typedef __attribute__((ext_vector_type(4)))  float  f32x4;
typedef __attribute__((ext_vector_type(16))) float  f32x16;
typedef __attribute__((ext_vector_type(8)))  __bf16 bf16x8;

union U128 { uint4 u4; bf16x8 b8; u16 us[8]; u32 u[4]; };

__device__ inline u16 f2bf(float f) {
  union { __bf16 h; u16 u; } c;
  c.h = (__bf16)f;
  return c.u;
}

__device__ inline float fexp2(float x) {
  float r;
  asm("v_exp_f32 %0, %1" : "=v"(r) : "v"(x));
  return r;
}

__device__ inline f32x4 mfma16(bf16x8 a, bf16x8 b, f32x4 c) {
  return __builtin_amdgcn_mfma_f32_16x16x32_bf16(a, b, c, 0, 0, 0);
}
__device__ inline f32x16 mfma32(bf16x8 a, bf16x8 b, f32x16 c) {
  return __builtin_amdgcn_mfma_f32_32x32x16_bf16(a, b, c, 0, 0, 0);
}

__device__ inline uint4 pack8bf(float4 a, float4 b) {
  U128 w;
  w.us[0] = f2bf(a.x); w.us[1] = f2bf(a.y);
  w.us[2] = f2bf(a.z); w.us[3] = f2bf(a.w);
  w.us[4] = f2bf(b.x); w.us[5] = f2bf(b.y);
  w.us[6] = f2bf(b.z); w.us[7] = f2bf(b.w);
  return w.u4;
}

// Fragment-major layouts (per batch, stride 262144 u16 = 512 KB):
//   Kfrag[(t2*8+ks)*512 + hi*256 + l31*8 + j]          = K[t2*32+l31][ks*16+hi*8+j]
//   Vfrag[((t2*4+vb2)*2+th)*512 + hi*256 + l31*8 + j]  = V[t2*32+th*16+hi*8+j][vb2*32+l31]
#define BSTRIDE 262144

// W fragment layout (B-operand of mfma16, frag-major):
//   Wfrag[((ks*16+nf)*64 + lane)*8 + j] = W[ks*32 + (lane>>4)*8 + j][nf*16 + (lane&15)]
// -> a wave's B-frag load = one global_load_dwordx4 covering a contiguous 1KB.

// ---------------------------------------------------------------------------
// Kernel 0: prep — [Wk|Wv] f32 -> bf16 B-fragment-major Wfrag (512 KB).
// ---------------------------------------------------------------------------
__global__ void __launch_bounds__(256) prep_kernel(
    const float* __restrict__ Wk, const float* __restrict__ Wv,
    u16* __restrict__ Wfrag)
{
  int T = blockIdx.x * 256 + threadIdx.x;   // 0..32767
  int lane = T & 63;
  int nf   = (T >> 6) & 15;
  int ks   = T >> 10;                       // 0..31
  int l15  = lane & 15;
  int g    = lane >> 4;
  int n    = nf * 16 + l15;
  const float* src = (n < 128) ? (Wk + n) : (Wv + (n - 128));
  int k0 = ks * 32 + g * 8;
  U128 w;
#pragma unroll
  for (int j = 0; j < 8; ++j) w.us[j] = f2bf(src[(size_t)(k0 + j) * KSZ]);
  *(uint4*)(Wfrag + (size_t)T * 8) = w.u4;
}

// ---------------------------------------------------------------------------
// Kernel 1: fused K/V projection — WAVE-AUTONOMOUS (zero barriers).
// 2048 waves; wave gw: rows m0=(gw>>1)*16, half nh=gw&1 (0=K cols, 1=V cols).
// Per ks (32 steps): A-frag from X (f32->bf16, 32B/lane), 8 B-frag 1KB loads
// from Wfrag, 8 mfma16. nh=0 wave also streams the out[:, :1024] passthrough.
// No __syncthreads => compiler software-pipelines loads across iterations
// with counted vmcnt. Epilogue: bias + per-wave 4KB LDS transpose (same-wave
// ds ordering, no barrier) -> frag-major Kfrag/Vfrag stores.
// ---------------------------------------------------------------------------
__global__ void __launch_bounds__(256) proj_kernel(
    const float* __restrict__ X, const u16* __restrict__ Wfrag,
    const float* __restrict__ bk, const float* __restrict__ bv,
    float* __restrict__ out, u16* __restrict__ Kfrag, u16* __restrict__ Vfrag)
{
  __shared__ u16 Ct[4][16 * 128];   // per-wave transpose scratch (4 KB each)

  const int tid  = threadIdx.x;
  const int lane = tid & 63;
  const int w    = tid >> 6;
  const int l15  = lane & 15;
  const int g    = lane >> 4;

  const int gw = blockIdx.x * 4 + w;   // 0..2047
  const int rt = gw >> 1;              // row-tile 0..1023
  const int nh = gw & 1;               // 0 = K half, 1 = V half
  const int m0 = rt * 16;

  const float* xrow = X + (size_t)(m0 + l15) * DMS + g * 8;
  float*       orow = out + (size_t)(m0 + l15) * OD + g * 8;
  const u16*   wbase = Wfrag + (size_t)(nh * 8) * 512 + lane * 8;

  f32x4 acc[8];
#pragma unroll
  for (int nf = 0; nf < 8; ++nf) acc[nf] = (f32x4){0.f, 0.f, 0.f, 0.f};

  float4 a0 = *(const float4*)(xrow);
  float4 a1 = *(const float4*)(xrow + 4);

#pragma unroll 2
  for (int ks = 0; ks < 32; ++ks) {
    float4 n0, n1;
    if (ks < 31) {
      n0 = *(const float4*)(xrow + (ks + 1) * 32);
      n1 = *(const float4*)(xrow + (ks + 1) * 32 + 4);
    }
    if (nh == 0) {
      *(float4*)(orow + ks * 32)     = a0;
      *(float4*)(orow + ks * 32 + 4) = a1;
    }
    U128 aw; aw.u4 = pack8bf(a0, a1);
    const u16* bp = wbase + (size_t)ks * 8192;   // ks*16*64*8
#pragma unroll
    for (int nf = 0; nf < 8; ++nf) {
      U128 u; u.u4 = *(const uint4*)(bp + nf * 512);
      acc[nf] = mfma16(aw.b8, u.b8, acc[nf]);
    }
    a0 = n0; a1 = n1;
  }

  // ---- epilogue: bias + swizzled per-wave LDS transpose ----
  const float* bias_src = nh ? bv : bk;
  u16* C = &Ct[w][0];
#pragma unroll
  for (int nf = 0; nf < 8; ++nf) {
    float bs = bias_src[nf * 16 + l15];
#pragma unroll
    for (int j = 0; j < 4; ++j) {
      int r = g * 4 + j;
      C[r * 128 + ((nf * 16 + l15) ^ ((r & 7) << 3))] = f2bf(acc[nf][j] + bs);
    }
  }
  // same-wave ds_write -> ds_read ordering: compiler inserts lgkmcnt waits

  const int b  = m0 >> 11;             // batch
  const int t2 = (m0 & 2047) >> 5;     // 32-row tile within batch
  const int rb = m0 & 16;              // 0 or 16: which half of t2

  if (nh == 0) {
    // ---- Kfrag: frag-major stores (16B per lane) ----
#pragma unroll
    for (int h = 0; h < 2; ++h) {
      int r   = (lane >> 3) + 8 * h;   // 0..15
      int ks2 = lane & 7;
      int l31 = rb + r;
      u16* dst = Kfrag + (size_t)b * BSTRIDE + (size_t)(t2 * 8 + ks2) * 512 + l31 * 8;
#pragma unroll
      for (int hi2 = 0; hi2 < 2; ++hi2) {
        uint4 v = *(const uint4*)&C[r * 128 + ((ks2 * 16 + hi2 * 8) ^ ((r & 7) << 3))];
        *(uint4*)(dst + hi2 * 256) = v;
      }
    }
  } else {
    // ---- Vfrag: column gather out of C (transpose) ----
    const int th   = rb >> 4;
    const int l31v = lane & 31;
    const int vbs  = lane >> 5;
#pragma unroll
    for (int t = 0; t < 2; ++t) {
      int vb2 = vbs + t * 2;
#pragma unroll
      for (int hi = 0; hi < 2; ++hi) {
        U128 wv;
#pragma unroll
        for (int j = 0; j < 8; ++j) {
          int r = hi * 8 + j;
          wv.us[j] = C[r * 128 + ((vb2 * 32 + l31v) ^ ((r & 7) << 3))];
        }
        u16* dst = Vfrag + (size_t)b * BSTRIDE +
                   (size_t)((t2 * 4 + vb2) * 2 + th) * 512 + hi * 256 + l31v * 8;
        *(uint4*)dst = wv.u4;
      }
    }
  }
}

// ---------------------------------------------------------------------------
// Kernel 2: causal flash attention (unchanged — verified passing).
// ---------------------------------------------------------------------------
__global__ void __launch_bounds__(256, 2) attn_kernel(
    const u16* __restrict__ Kfrag, const u16* __restrict__ Vfrag,
    float* __restrict__ out)
{
  __shared__ float Om[4][128][33];   // [slice][v][q] partial O^T
  __shared__ float Ml[4][2][32];     // [slice][m|l][q]
  __shared__ float Wm[4][32];        // merge weights
  __shared__ float Li[32];           // 1/L

  const int tid  = threadIdx.x;
  const int lane = tid & 63;
  const int w    = tid >> 6;         // KV slice 0..3
  const int l31  = lane & 31;
  const int hi   = lane >> 5;

  const int bi = blockIdx.x;
  const int b  = bi & 7;
  const int qt = (bi < 256) ? (63 - (bi >> 3)) : ((bi >> 3) - 32);
  const int q0 = qt * 32;

  const u16* Kb = Kfrag + (size_t)b * BSTRIDE;
  const u16* Vb = Vfrag + (size_t)b * BSTRIDE;
  const int loff = hi * 256 + l31 * 8;   // lane offset within a 512-u16 frag

  bf16x8 qf[8];
  {
    const u16* qp = Kb + (size_t)(qt * 8) * 512 + loff;
#pragma unroll
    for (int ks = 0; ks < 8; ++ks) {
      U128 u; u.u4 = *(const uint4*)(qp + ks * 512); qf[ks] = u.b8;
    }
  }

  f32x16 o[4];
#pragma unroll
  for (int vb2 = 0; vb2 < 4; ++vb2)
#pragma unroll
    for (int i = 0; i < 16; ++i) o[vb2][i] = 0.f;

  float mrun = -3.0e38f, lsum = 0.f;
  const float SC  = 0.08838834764831845f;   // 1/sqrt(128)
  const float L2E = 1.44269504088896341f;

  bf16x8 kf[8];
  {
    int ti0 = (w <= qt) ? w : 0;
    const u16* kp = Kb + (size_t)(ti0 * 8) * 512 + loff;
#pragma unroll
    for (int ks = 0; ks < 8; ++ks) {
      U128 u; u.u4 = *(const uint4*)(kp + ks * 512); kf[ks] = u.b8;
    }
  }

  for (int ti = w; ti <= qt; ti += 4) {
    bf16x8 vf[4][2];
    {
      const u16* vp = Vb + (size_t)(ti * 8) * 512 + loff;
#pragma unroll
      for (int vb2 = 0; vb2 < 4; ++vb2)
#pragma unroll
        for (int th = 0; th < 2; ++th) {
          U128 u; u.u4 = *(const uint4*)(vp + (vb2 * 2 + th) * 512);
          vf[vb2][th] = u.b8;
        }
    }
    f32x16 s;
#pragma unroll
    for (int i = 0; i < 16; ++i) s[i] = 0.f;
#pragma unroll
    for (int ks = 0; ks < 8; ++ks) s = mfma32(kf[ks], qf[ks], s);
    {
      int tin = (ti + 4 <= qt) ? ti + 4 : ti;
      const u16* kp = Kb + (size_t)(tin * 8) * 512 + loff;
#pragma unroll
      for (int ks = 0; ks < 8; ++ks) {
        U128 u; u.u4 = *(const uint4*)(kp + ks * 512); kf[ks] = u.b8;
      }
    }
    float sv[16];
#pragma unroll
    for (int r = 0; r < 16; ++r) sv[r] = s[r] * SC;
    if (ti == qt) {
#pragma unroll
      for (int r = 0; r < 16; ++r) {
        int toff = (r & 3) + 8 * (r >> 2) + 4 * hi;
        if (toff > l31) sv[r] = -3.0e38f;
      }
    }
    float mx = sv[0];
#pragma unroll
    for (int r = 1; r < 16; ++r) mx = fmaxf(mx, sv[r]);
    mx = fmaxf(mx, __shfl_xor(mx, 32));
    float p[16];
    float ps = 0.f;
    if (__all(mx - mrun <= 8.0f)) {
#pragma unroll
      for (int r = 0; r < 16; ++r) { p[r] = fexp2((sv[r] - mrun) * L2E); ps += p[r]; }
      ps += __shfl_xor(ps, 32);
      lsum += ps;
    } else {
      float mnew = fmaxf(mrun, mx);
      float al = fexp2((mrun - mnew) * L2E);
#pragma unroll
      for (int r = 0; r < 16; ++r) { p[r] = fexp2((sv[r] - mnew) * L2E); ps += p[r]; }
      ps += __shfl_xor(ps, 32);
      lsum = lsum * al + ps;
      mrun = mnew;
#pragma unroll
      for (int vb2 = 0; vb2 < 4; ++vb2)
#pragma unroll
        for (int i = 0; i < 16; ++i) o[vb2][i] *= al;
    }
    u32 c01 = (u32)f2bf(p[0])  | ((u32)f2bf(p[1])  << 16);
    u32 c23 = (u32)f2bf(p[2])  | ((u32)f2bf(p[3])  << 16);
    u32 c45 = (u32)f2bf(p[4])  | ((u32)f2bf(p[5])  << 16);
    u32 c67 = (u32)f2bf(p[6])  | ((u32)f2bf(p[7])  << 16);
    u32 c89 = (u32)f2bf(p[8])  | ((u32)f2bf(p[9])  << 16);
    u32 cAB = (u32)f2bf(p[10]) | ((u32)f2bf(p[11]) << 16);
    u32 cCD = (u32)f2bf(p[12]) | ((u32)f2bf(p[13]) << 16);
    u32 cEF = (u32)f2bf(p[14]) | ((u32)f2bf(p[15]) << 16);
    u32 d01 = __shfl_xor(c01, 32);
    u32 d23 = __shfl_xor(c23, 32);
    u32 d45 = __shfl_xor(c45, 32);
    u32 d67 = __shfl_xor(c67, 32);
    u32 d89 = __shfl_xor(c89, 32);
    u32 dAB = __shfl_xor(cAB, 32);
    u32 dCD = __shfl_xor(cCD, 32);
    u32 dEF = __shfl_xor(cEF, 32);
    U128 pf1, pf2;
    pf1.u[0] = hi ? d45 : c01;
    pf1.u[1] = hi ? d67 : c23;
    pf1.u[2] = hi ? c45 : d01;
    pf1.u[3] = hi ? c67 : d23;
    pf2.u[0] = hi ? dCD : c89;
    pf2.u[1] = hi ? dEF : cAB;
    pf2.u[2] = hi ? cCD : d89;
    pf2.u[3] = hi ? cEF : dAB;
#pragma unroll
    for (int vb2 = 0; vb2 < 4; ++vb2) {
      o[vb2] = mfma32(vf[vb2][0], pf1.b8, o[vb2]);
      o[vb2] = mfma32(vf[vb2][1], pf2.b8, o[vb2]);
    }
  }

#pragma unroll
  for (int vb2 = 0; vb2 < 4; ++vb2)
#pragma unroll
    for (int r = 0; r < 16; ++r) {
      int v = vb2 * 32 + (r & 3) + 8 * (r >> 2) + 4 * hi;
      Om[w][v][l31] = o[vb2][r];
    }
  if (lane < 32) {
    Ml[w][0][l31] = mrun;
    Ml[w][1][l31] = lsum;
  }
  __syncthreads();

  if (tid < 32) {
    float m0 = Ml[0][0][tid], m1 = Ml[1][0][tid];
    float m2 = Ml[2][0][tid], m3 = Ml[3][0][tid];
    float M  = fmaxf(fmaxf(m0, m1), fmaxf(m2, m3));
    float w0 = fexp2((m0 - M) * L2E), w1 = fexp2((m1 - M) * L2E);
    float w2 = fexp2((m2 - M) * L2E), w3 = fexp2((m3 - M) * L2E);
    float L  = Ml[0][1][tid] * w0 + Ml[1][1][tid] * w1 +
               Ml[2][1][tid] * w2 + Ml[3][1][tid] * w3;
    Wm[0][tid] = w0; Wm[1][tid] = w1; Wm[2][tid] = w2; Wm[3][tid] = w3;
    Li[tid] = 1.f / L;
  }
  __syncthreads();

  {
    const int q = tid >> 3;
    const int vbase = (tid & 7) * 16;
    float wq0 = Wm[0][q], wq1 = Wm[1][q], wq2 = Wm[2][q], wq3 = Wm[3][q];
    float li = Li[q];
    float* orow = out + (size_t)(b * SEQ + q0 + q) * OD + 1024 + vbase;
#pragma unroll
    for (int i = 0; i < 16; i += 4) {
      float4 res;
      res.x = (Om[0][vbase + i + 0][q] * wq0 + Om[1][vbase + i + 0][q] * wq1 +
               Om[2][vbase + i + 0][q] * wq2 + Om[3][vbase + i + 0][q] * wq3) * li;
      res.y = (Om[0][vbase + i + 1][q] * wq0 + Om[1][vbase + i + 1][q] * wq1 +
               Om[2][vbase + i + 1][q] * wq2 + Om[3][vbase + i + 1][q] * wq3) * li;
      res.z = (Om[0][vbase + i + 2][q] * wq0 + Om[1][vbase + i + 2][q] * wq1 +
               Om[2][vbase + i + 2][q] * wq2 + Om[3][vbase + i + 2][q] * wq3) * li;
      res.w = (Om[0][vbase + i + 3][q] * wq0 + Om[1][vbase + i + 3][q] * wq1 +
               Om[2][vbase + i + 3][q] * wq2 + Om[3][vbase + i + 3][q] * wq3) * li;
      *(float4*)(orow + i) = res;
    }
  }
}

extern "C" void kernel_launch(void* const* d_in, const int* in_sizes, int n_in,
                              void* d_out, int out_size, void* d_ws, size_t ws_size,
                              hipStream_t stream)
{
  const float* X  = (const float*)d_in[0];
  const float* Wk = (const float*)d_in[1];
  const float* bk = (const float*)d_in[2];
  const float* Wv = (const float*)d_in[3];
  const float* bv = (const float*)d_in[4];
  float* out = (float*)d_out;

  u16* Kfrag = (u16*)d_ws;                                // 4 MB
  u16* Vfrag = Kfrag + (size_t)BATCH * BSTRIDE;           // 4 MB
  u16* Wfrag = Vfrag + (size_t)BATCH * BSTRIDE;           // 512 KB

  prep_kernel<<<dim3(128), dim3(256), 0, stream>>>(Wk, Wv, Wfrag);
  proj_kernel<<<dim3(512), dim3(256), 0, stream>>>(X, Wfrag, bk, bv, out, Kfrag, Vfrag);
  attn_kernel<<<dim3(512), dim3(256), 0, stream>>>(Kfrag, Vfrag, out);
}